// Round 4
// baseline (228.768 us; speedup 1.0000x reference)
//
#include <hip/hip_runtime.h>

#define NN 50000
#define TOPK 32
#define IN_C 128
#define OUT_C 64
#define NEG_SLOPE 0.2f
#define BN_EPS 1e-5f

// K1: lane = channel, W row resident in VGPRs, x via wave-uniform (scalar)
// loads. 2 nodes per wave-iteration for fma dual-issue ILP.
#define K1_BLOCKS 768
#define K1_WAVES (K1_BLOCKS * 4)

// K2: 8 nodes per wave (8 lanes per node), exactly one task per wave
#define NTASK (NN / 8)              // 6250
#define K2_BLOCKS ((NTASK + 3) / 4) // 1563

// workspace layout (floats)
#define WS_XBF   0                       // bf16 x_lin: NN*64*2B = NN*32 floats
#define WS_AI    (NN * 32)
#define WS_AJ    (WS_AI + NN)
#define WS_SUMS  (WS_AJ + NN)            // 128
#define WS_STATS (WS_SUMS + 128)         // 128

__device__ inline float leaky(float a) { return a >= 0.f ? a : NEG_SLOPE * a; }

__device__ inline unsigned short f2bf(float f) {     // RNE fp32 -> bf16
    unsigned u = __float_as_uint(f);
    unsigned r = (u + 0x7fffu + ((u >> 16) & 1u)) >> 16;
    return (unsigned short)r;
}

// K1: x_lin(bf16) = x @ lin_w^T, plus a_i/a_j. No LDS at all: weights live
// in VGPRs (lane = out channel), x rows are wave-uniform scalar loads
// (SMEM pipe). Also zeroes the BN sums buffer (replaces memset dispatch).
__global__ __launch_bounds__(256) void k1_linear(
    const float* __restrict__ x, const float* __restrict__ emb,
    const float* __restrict__ lin_w,
    const float* __restrict__ att_i, const float* __restrict__ att_j,
    const float* __restrict__ att_em_i, const float* __restrict__ att_em_j,
    unsigned short* __restrict__ x_bf, float* __restrict__ a_i,
    float* __restrict__ a_j, float* __restrict__ sums)
{
    const int tid = threadIdx.x;
    if (blockIdx.x == 0 && tid < 128) sums[tid] = 0.f;   // k2 runs after k1

    const int lane = tid & 63;
    const int gw = blockIdx.x * 4 + (tid >> 6);

    // W row for this lane's channel: 128 floats in VGPRs
    float wreg[IN_C];
    {
        const float4* wr = (const float4*)(lin_w + lane * IN_C);
        float4* wd = (float4*)wreg;
#pragma unroll
        for (int i = 0; i < IN_C / 4; ++i) wd[i] = wr[i];
    }
    const float ai_c = att_i[lane], aj_c = att_j[lane];
    const float aei_c = att_em_i[lane], aej_c = att_em_j[lane];

    for (int n0 = gw * 2; n0 < NN; n0 += K1_WAVES * 2) {
        const float4* xa4 = (const float4*)(x + (size_t)n0 * IN_C);
        const float4* xb4 = xa4 + IN_C / 4;
        float acc0 = 0.f, acc1 = 0.f;
#pragma unroll
        for (int k4 = 0; k4 < IN_C / 4; ++k4) {
            const float4 xa = xa4[k4];           // wave-uniform -> s_load
            const float4 xb = xb4[k4];
            acc0 = fmaf(wreg[k4 * 4 + 0], xa.x, acc0);
            acc1 = fmaf(wreg[k4 * 4 + 0], xb.x, acc1);
            acc0 = fmaf(wreg[k4 * 4 + 1], xa.y, acc0);
            acc1 = fmaf(wreg[k4 * 4 + 1], xb.y, acc1);
            acc0 = fmaf(wreg[k4 * 4 + 2], xa.z, acc0);
            acc1 = fmaf(wreg[k4 * 4 + 2], xb.z, acc1);
            acc0 = fmaf(wreg[k4 * 4 + 3], xa.w, acc0);
            acc1 = fmaf(wreg[k4 * 4 + 3], xb.w, acc1);
        }
#pragma unroll
        for (int h = 0; h < 2; ++h) {
            const int n = n0 + h;
            const float y = h ? acc1 : acc0;
            x_bf[(size_t)n * OUT_C + lane] = f2bf(y);
            const float e = emb[(size_t)n * OUT_C + lane];
            float vi = fmaf(y, ai_c, e * aei_c);
            float vj = fmaf(y, aj_c, e * aej_c);
#pragma unroll
            for (int d = 1; d < 64; d <<= 1) {
                vi += __shfl_xor(vi, d, 64);
                vj += __shfl_xor(vj, d, 64);
            }
            if (lane == 0) { a_i[n] = vi; a_j[n] = vj; }
        }
    }
}

// K2: lane = (g = lane>>3 node-of-8, q = lane&7 row-slice). One task (8
// nodes) per wave. src loaded as int4 (4 edges/instr); gathers are uint4
// (8 bf16 channels = 16 B/lane, 8 lanes cover a full 128 B row).
__global__ __launch_bounds__(256) void k2_attn(
    const int* __restrict__ src,
    const uint4* __restrict__ x_bf, const float* __restrict__ a_i,
    const float* __restrict__ a_j, const float* __restrict__ bias,
    float* __restrict__ out, float* __restrict__ sums)
{
    const int tid = threadIdx.x;
    const int lane = tid & 63;
    const int wv = tid >> 6;
    const int task = blockIdx.x * 4 + wv;
    const int g = lane >> 3;
    const int q = lane & 7;
    const int gb = lane & 56;

    float v[8];
#pragma unroll
    for (int j = 0; j < 8; ++j) v[j] = 0.f;
    bool active = (task < NTASK);

    if (active) {
        const int t = task * 8 + g;
        const float ai_t = a_i[t];
        const float sal = leaky(ai_t + a_j[t]);            // self edge
        const int4 sv = ((const int4*)src)[t * (TOPK / 4) + q];
        float al0 = leaky(ai_t + a_j[sv.x]);
        float al1 = leaky(ai_t + a_j[sv.y]);
        float al2 = leaky(ai_t + a_j[sv.z]);
        float al3 = leaky(ai_t + a_j[sv.w]);

        float m = fmaxf(fmaxf(al0, al1), fmaxf(al2, al3));
#pragma unroll
        for (int d = 1; d < 8; d <<= 1) m = fmaxf(m, __shfl_xor(m, d, 64));
        m = fmaxf(m, sal);
        float w0 = __expf(al0 - m), w1 = __expf(al1 - m);
        float w2 = __expf(al2 - m), w3 = __expf(al3 - m);
        const float es = __expf(sal - m);
        float den = (w0 + w1) + (w2 + w3);
#pragma unroll
        for (int d = 1; d < 8; d <<= 1) den += __shfl_xor(den, d, 64);
        den += es + 1e-16f;
        const float inv = 1.f / den;
        w0 *= inv; w1 *= inv; w2 *= inv; w3 *= inv;
        const float wself = es * inv;

        float A0[8], A1[8], A2[8], A3[8];
#pragma unroll
        for (int j = 0; j < 8; ++j) { A0[j] = A1[j] = A2[j] = A3[j] = 0.f; }

#define GATHER8(A, W, S)                                                      \
        {                                                                     \
            const uint4 u = x_bf[(size_t)(S) * 8 + q];                        \
            A[0] = fmaf(W, __uint_as_float(u.x << 16), A[0]);                 \
            A[1] = fmaf(W, __uint_as_float(u.x & 0xffff0000u), A[1]);         \
            A[2] = fmaf(W, __uint_as_float(u.y << 16), A[2]);                 \
            A[3] = fmaf(W, __uint_as_float(u.y & 0xffff0000u), A[3]);         \
            A[4] = fmaf(W, __uint_as_float(u.z << 16), A[4]);                 \
            A[5] = fmaf(W, __uint_as_float(u.z & 0xffff0000u), A[5]);         \
            A[6] = fmaf(W, __uint_as_float(u.w << 16), A[6]);                 \
            A[7] = fmaf(W, __uint_as_float(u.w & 0xffff0000u), A[7]);         \
        }

#pragma unroll
        for (int o = 0; o < 8; ++o) {       // owner lane offset in group
            const float we0 = __shfl(w0, gb + o, 64); const int se0 = __shfl(sv.x, gb + o, 64);
            const float we1 = __shfl(w1, gb + o, 64); const int se1 = __shfl(sv.y, gb + o, 64);
            const float we2 = __shfl(w2, gb + o, 64); const int se2 = __shfl(sv.z, gb + o, 64);
            const float we3 = __shfl(w3, gb + o, 64); const int se3 = __shfl(sv.w, gb + o, 64);
            GATHER8(A0, we0, se0);
            GATHER8(A1, we1, se1);
            GATHER8(A2, we2, se2);
            GATHER8(A3, we3, se3);
        }
        GATHER8(A0, wself, t);              // self loop
#undef GATHER8

        const float4 b0 = ((const float4*)bias)[q * 2];
        const float4 b1 = ((const float4*)bias)[q * 2 + 1];
        v[0] = (A0[0] + A1[0]) + (A2[0] + A3[0]) + b0.x;
        v[1] = (A0[1] + A1[1]) + (A2[1] + A3[1]) + b0.y;
        v[2] = (A0[2] + A1[2]) + (A2[2] + A3[2]) + b0.z;
        v[3] = (A0[3] + A1[3]) + (A2[3] + A3[3]) + b0.w;
        v[4] = (A0[4] + A1[4]) + (A2[4] + A3[4]) + b1.x;
        v[5] = (A0[5] + A1[5]) + (A2[5] + A3[5]) + b1.y;
        v[6] = (A0[6] + A1[6]) + (A2[6] + A3[6]) + b1.z;
        v[7] = (A0[7] + A1[7]) + (A2[7] + A3[7]) + b1.w;
        float4* o4 = (float4*)(out + (size_t)t * OUT_C + q * 8);
        o4[0] = make_float4(v[0], v[1], v[2], v[3]);
        o4[1] = make_float4(v[4], v[5], v[6], v[7]);
    }

    // block BN reduction: channel c = q*8+j, 32 (wave,group) slots
    __shared__ float sb1[64][33];
    __shared__ float sb2[64][33];
    const int slot = wv * 8 + g;
#pragma unroll
    for (int j = 0; j < 8; ++j) {
        const float val = active ? v[j] : 0.f;
        sb1[q * 8 + j][slot] = val;
        sb2[q * 8 + j][slot] = val * val;
    }
    __syncthreads();
    if (tid < 64) {
        float t1 = 0.f, t2 = 0.f;
#pragma unroll
        for (int r = 0; r < 32; ++r) { t1 += sb1[tid][r]; t2 += sb2[tid][r]; }
        atomicAdd(&sums[tid], t1);
        atomicAdd(&sums[64 + tid], t2);
    }
}

__global__ __launch_bounds__(64) void k3_stats(
    const float* __restrict__ sums, const float* __restrict__ gamma,
    const float* __restrict__ beta, float* __restrict__ stats)
{
    const int c = threadIdx.x;
    const float mu = sums[c] / (float)NN;
    const float ex2 = sums[64 + c] / (float)NN;
    const float var = fmaxf(ex2 - mu * mu, 0.f);
    const float sc = gamma[c] / sqrtf(var + BN_EPS);
    stats[c] = sc;
    stats[64 + c] = beta[c] - mu * sc;
}

__global__ __launch_bounds__(256) void k4_bn(
    float* __restrict__ out, const float* __restrict__ stats)
{
    __shared__ float s_sc[64], s_sh[64];
    const int tid = threadIdx.x;
    if (tid < 64) { s_sc[tid] = stats[tid]; s_sh[tid] = stats[64 + tid]; }
    __syncthreads();
    const size_t total = (size_t)NN * OUT_C / 4;
    float4* p = (float4*)out;
    for (size_t idx = (size_t)blockIdx.x * 256 + tid; idx < total;
         idx += (size_t)gridDim.x * 256) {
        float4 v = p[idx];
        const int c0 = (int)((idx * 4) & 63);
        v.x = fmaxf(fmaf(v.x, s_sc[c0 + 0], s_sh[c0 + 0]), 0.f);
        v.y = fmaxf(fmaf(v.y, s_sc[c0 + 1], s_sh[c0 + 1]), 0.f);
        v.z = fmaxf(fmaf(v.z, s_sc[c0 + 2], s_sh[c0 + 2]), 0.f);
        v.w = fmaxf(fmaf(v.w, s_sc[c0 + 3], s_sh[c0 + 3]), 0.f);
        p[idx] = v;
    }
}

extern "C" void kernel_launch(void* const* d_in, const int* in_sizes, int n_in,
                              void* d_out, int out_size, void* d_ws, size_t ws_size,
                              hipStream_t stream) {
    const float* x        = (const float*)d_in[0];
    const float* emb      = (const float*)d_in[1];
    const int*   edge     = (const int*)d_in[2];   // row 0 = src
    const float* lin_w    = (const float*)d_in[3];
    const float* att_i    = (const float*)d_in[4];
    const float* att_j    = (const float*)d_in[5];
    const float* att_em_i = (const float*)d_in[6];
    const float* att_em_j = (const float*)d_in[7];
    const float* bias     = (const float*)d_in[8];
    const float* gamma    = (const float*)d_in[9];
    const float* beta     = (const float*)d_in[10];

    float* ws    = (float*)d_ws;
    unsigned short* x_bf = (unsigned short*)(ws + WS_XBF);
    float* a_i   = ws + WS_AI;
    float* a_j   = ws + WS_AJ;
    float* sums  = ws + WS_SUMS;
    float* stats = ws + WS_STATS;
    float* out   = (float*)d_out;

    k1_linear<<<K1_BLOCKS, 256, 0, stream>>>(x, emb, lin_w, att_i, att_j,
                                             att_em_i, att_em_j, x_bf, a_i, a_j, sums);
    k2_attn<<<K2_BLOCKS, 256, 0, stream>>>(edge, (const uint4*)x_bf, a_i, a_j,
                                           bias, out, sums);
    k3_stats<<<1, 64, 0, stream>>>(sums, gamma, beta, stats);
    k4_bn<<<3125, 256, 0, stream>>>(out, stats);
}